// Round 10
// baseline (238.699 us; speedup 1.0000x reference)
//
#include <hip/hip_runtime.h>
#include <hip/hip_bf16.h>
#include <stdint.h>
#include <stddef.h>

#define NB 2
#define SEQ 2048
#define HIDN 1024
#define NHEAD 16
#define HDIM 64
#define MTOT (NB * SEQ)   // 4096

typedef short bf16x8 __attribute__((ext_vector_type(8)));
typedef _Float16 f16x8 __attribute__((ext_vector_type(8)));
typedef __fp16 h16x2 __attribute__((ext_vector_type(2)));
typedef float f32x4 __attribute__((ext_vector_type(4)));
typedef uint32_t u32x4 __attribute__((ext_vector_type(4)));

#define MFMA16(a, b, c)  __builtin_amdgcn_mfma_f32_16x16x32_bf16(a, b, c, 0, 0, 0)
#define MFMAH16(a, b, c) __builtin_amdgcn_mfma_f32_16x16x32_f16(a, b, c, 0, 0, 0)

__device__ __forceinline__ unsigned short f2bf(float f) {
  union { float f; uint32_t u; } v; v.f = f;
  uint32_t u = v.u;
  uint32_t r = (u + 0x7fffu + ((u >> 16) & 1u)) >> 16;
  return (unsigned short)r;
}

__device__ __forceinline__ unsigned short f2h(float f) {
  _Float16 h = (_Float16)f;
  return *reinterpret_cast<unsigned short*>(&h);
}

__device__ __forceinline__ float h2f(unsigned short u) {
  _Float16 h = *reinterpret_cast<_Float16*>(&u);
  return (float)h;
}

__device__ __forceinline__ void gload16(const void* g, void* l) {
  __builtin_amdgcn_global_load_lds((const __attribute__((address_space(1))) void*)g,
                                   (__attribute__((address_space(3))) void*)l,
                                   16, 0, 0);
}

// ---------------- kernel 1: fp32 -> bf16 conversion ----------------
__global__ void cvt_bf16(const float* __restrict__ x, const float* __restrict__ wq,
                         const float* __restrict__ wk, const float* __restrict__ wv,
                         unsigned short* __restrict__ dst)
{
  size_t i4 = ((size_t)blockIdx.x * blockDim.x + threadIdx.x) * 4;
  const float* s; size_t off;
  if (i4 < 4194304UL)      { s = x;  off = i4; }
  else if (i4 < 5242880UL) { s = wq; off = i4 - 4194304UL; }
  else if (i4 < 6291456UL) { s = wk; off = i4 - 5242880UL; }
  else                     { s = wv; off = i4 - 6291456UL; }
  float4 v = *(const float4*)(s + off);
  ushort4 o;
  o.x = f2bf(v.x); o.y = f2bf(v.y); o.z = f2bf(v.z); o.w = f2bf(v.w);
  *(ushort4*)(dst + i4) = o;
}

// ---------------- kernel 2: QKV projection GEMM ----------------
// z=0: Qb bf16 (plain).
// z=1: Kb bf16, row-permuted + column-XOR-swizzled (16B slots) per head strip.
// z=2: Vt fp16 transposed [d][token], token-slot XOR-swizzled per 128-token seg.
__global__ __launch_bounds__(256, 2) void qkv_gemm(
    const unsigned short* __restrict__ xb,
    const unsigned short* __restrict__ wqb,
    const unsigned short* __restrict__ wkb,
    const unsigned short* __restrict__ wvb,
    unsigned short* __restrict__ Qb,
    unsigned short* __restrict__ Kb,
    unsigned short* __restrict__ Vt)
{
  __shared__ unsigned short As[128 * 64];
  __shared__ unsigned short Bs[128 * 64];

  const int z = blockIdx.z;
  const unsigned short* W = (z == 0) ? wqb : (z == 1) ? wkb : wvb;
  const int n0 = blockIdx.x * 128;
  const int m0 = blockIdx.y * 128;
  const int tid = threadIdx.x;
  const int lane = tid & 63;
  const int wid = tid >> 6;
  const int l15 = lane & 15;
  const int lg = lane >> 4;

  f32x4 acc[4][4] = {};

  const int wr = (wid >> 1) * 64;
  const int wc = (wid & 1) * 64;

  for (int kt = 0; kt < 16; ++kt) {
    __syncthreads();
    #pragma unroll
    for (int i = 0; i < 4; ++i) {
      int row = wid * 32 + i * 8 + (lane >> 3);
      int chunk = (lane & 7) ^ (row & 7);
      const unsigned short* ga = xb + (size_t)(m0 + row) * HIDN + kt * 64 + chunk * 8;
      const unsigned short* gb = W  + (size_t)(n0 + row) * HIDN + kt * 64 + chunk * 8;
      gload16(ga, (char*)As + wid * 4096 + i * 1024);
      gload16(gb, (char*)Bs + wid * 4096 + i * 1024);
    }
    __syncthreads();

    #pragma unroll
    for (int ks = 0; ks < 2; ++ks) {
      bf16x8 af[4], bfr[4];
      #pragma unroll
      for (int mi = 0; mi < 4; ++mi) {
        int row = wr + mi * 16 + l15;
        int cb = (ks * 64 + lg * 16) ^ ((row & 7) << 4);
        af[mi] = *(const bf16x8*)((const char*)As + row * 128 + cb);
      }
      #pragma unroll
      for (int ni = 0; ni < 4; ++ni) {
        int row = wc + ni * 16 + l15;
        int cb = (ks * 64 + lg * 16) ^ ((row & 7) << 4);
        bfr[ni] = *(const bf16x8*)((const char*)Bs + row * 128 + cb);
      }
      #pragma unroll
      for (int mi = 0; mi < 4; ++mi)
        #pragma unroll
        for (int ni = 0; ni < 4; ++ni)
          acc[mi][ni] = MFMA16(af[mi], bfr[ni], acc[mi][ni]);
    }
  }

  if (z < 2) {
    unsigned short* O = (z == 0) ? Qb : Kb;
    #pragma unroll
    for (int mi = 0; mi < 4; ++mi)
      #pragma unroll
      for (int ni = 0; ni < 4; ++ni) {
        int n = n0 + wc + ni * 16 + l15;
        #pragma unroll
        for (int e = 0; e < 4; ++e) {
          int m = m0 + wr + mi * 16 + lg * 4 + e;
          if (z == 0) {
            O[(size_t)m * HIDN + n] = f2bf(acc[mi][ni][e]);
          } else {
            int mm = (m & ~31) | (((m >> 2) & 1) << 4) | (((m >> 3) & 3) << 2) | (m & 3);
            int nn = (n & ~56) | (((((n >> 3) & 7) ^ (mm & 7))) << 3);
            O[(size_t)mm * HIDN + nn] = f2bf(acc[mi][ni][e]);
          }
        }
      }
  } else {
    #pragma unroll
    for (int mi = 0; mi < 4; ++mi)
      #pragma unroll
      for (int ni = 0; ni < 4; ++ni) {
        int n = n0 + wc + ni * 16 + l15;          // output channel d
        int m = m0 + wr + mi * 16 + lg * 4;        // token (mult of 4)
        int mmv = (m & ~120) | (((((m >> 3) & 15) ^ (n & 15))) << 3);
        ushort4 pk;
        pk.x = f2h(acc[mi][ni][0]);
        pk.y = f2h(acc[mi][ni][1]);
        pk.z = f2h(acc[mi][ni][2]);
        pk.w = f2h(acc[mi][ni][3]);
        *(ushort4*)(Vt + (size_t)n * MTOT + mmv) = pk;
      }
  }
}

// ---------------- kernel 3: attn_all — sums + PV + emit in ONE pass --------
// 512 threads = 8 waves; block owns 128 q-rows of one XCD-pinned (b,h) panel,
// processed as 8 tiles of 16 rows. Per tile: QK+exp once (K from L2, swizzle-
// decoded), P kept in regs AND packed to 64KB LDS; row sums via shfl + tiny
// LDS reduce -> inv; PV from regs vs V (L2, swizzle-decoded); emit full
// 8KB-contiguous normalized fp32 rows (stores never vmcnt-gated); cross-wave
// PV reduce through the now-dead P area; attv stored per tile.
__global__ __launch_bounds__(512, 2) void attn_all(
    const unsigned short* __restrict__ Qb,
    const unsigned short* __restrict__ Kb,
    const unsigned short* __restrict__ Vt,
    float* __restrict__ out)
{
  __shared__ unsigned short P[16 * 2048];   // 64KB
  __shared__ float sums[8][16];

  const int bid = blockIdx.x;            // 0..511
  const int xcd = bid & 7;
  const int rest = bid >> 3;             // 0..63
  const int pan = (rest & 3) * 8 + xcd;  // XCD-pinned (b,h) panel 0..31
  const int blkp = rest >> 2;            // 0..15
  const int b = pan >> 4, h = pan & 15;
  const int tid = threadIdx.x;
  const int wid = tid >> 6;
  const int lane = tid & 63;
  const int l15 = lane & 15, lg = lane >> 4;

  const float C = 0.18033688011112042f;  // (1/8) * log2(e)
  const unsigned short* kpanel = Kb + (size_t)b * SEQ * HIDN + h * HDIM;
  const unsigned short* vpanel = Vt + (size_t)h * HDIM * MTOT + b * SEQ;
  const size_t panrow0 = (size_t)(b * NHEAD + h) * SEQ;
  float* avbase = out + (size_t)NB * NHEAD * SEQ * SEQ;

  for (int tt = 0; tt < 8; ++tt) {
    const int q0 = blkp * 128 + tt * 16;

    const unsigned short* qptr = Qb + ((size_t)(b * SEQ + q0 + l15) * HIDN + h * HDIM + lg * 8);
    const bf16x8 bq0 = *(const bf16x8*)qptr;
    const bf16x8 bq1 = *(const bf16x8*)(qptr + 32);

    // ---- phase a: QK + exp, pack P (LDS + regs), partial sums ----
    union PKu { h16x2 h2[4]; f16x8 h8; u32x4 u4; };
    u32x4 pkreg[2][4];
    float sm = 0.f;

    #pragma unroll
    for (int i = 0; i < 2; ++i) {
      const int c = wid * 2 + i;
      f32x4 acc[8] = {};
      #pragma unroll
      for (int kf = 0; kf < 8; ++kf) {
        const int s = c * 128 + kf * 16 + l15;     // storage row
        const unsigned short* kr = kpanel + (size_t)s * HIDN;
        bf16x8 a0 = *(const bf16x8*)(kr + ((lg      ^ (s & 7))) * 8);
        bf16x8 a1 = *(const bf16x8*)(kr + (((lg + 4) ^ (s & 7))) * 8);
        acc[kf] = MFMA16(a0, bq0, acc[kf]);
        acc[kf] = MFMA16(a1, bq1, acc[kf]);
      }
      #pragma unroll
      for (int t = 0; t < 4; ++t) {
        float4 s0, s1;
        s0.x = exp2f(acc[2 * t][0] * C);
        s0.y = exp2f(acc[2 * t][1] * C);
        s0.z = exp2f(acc[2 * t][2] * C);
        s0.w = exp2f(acc[2 * t][3] * C);
        s1.x = exp2f(acc[2 * t + 1][0] * C);
        s1.y = exp2f(acc[2 * t + 1][1] * C);
        s1.z = exp2f(acc[2 * t + 1][2] * C);
        s1.w = exp2f(acc[2 * t + 1][3] * C);
        sm += ((s0.x + s0.y) + (s0.z + s0.w)) + ((s1.x + s1.y) + (s1.z + s1.w));

        PKu pk;
        pk.h2[0] = __builtin_amdgcn_cvt_pkrtz(s0.x, s0.y);
        pk.h2[1] = __builtin_amdgcn_cvt_pkrtz(s0.z, s0.w);
        pk.h2[2] = __builtin_amdgcn_cvt_pkrtz(s1.x, s1.y);
        pk.h2[3] = __builtin_amdgcn_cvt_pkrtz(s1.z, s1.w);
        pkreg[i][t] = pk.u4;

        const int off = c * 256 + ((((t * 4 + lg) ^ l15)) << 4);
        *(u32x4*)((char*)P + l15 * 4096 + off) = pk.u4;
      }
    }
    // partial sums over lane-groups (4 lanes share q=l15)
    sm += __shfl_xor(sm, 16, 64);
    sm += __shfl_xor(sm, 32, 64);
    if (lane < 16) sums[wid][lane] = sm;

    asm volatile("s_waitcnt lgkmcnt(0)" ::: "memory");
    __builtin_amdgcn_s_barrier();             // bar1: P + sums visible
    __builtin_amdgcn_sched_barrier(0);

    // inv for q = l15
    float tot = 0.f;
    #pragma unroll
    for (int w2 = 0; w2 < 8; ++w2) tot += sums[w2][l15];
    const float inv = __builtin_amdgcn_rcpf(tot);

    // ---- phase b: PV from regs vs V (global L2, swizzle-decoded) ----
    f32x4 pv[4] = {};
    #pragma unroll
    for (int i = 0; i < 2; ++i) {
      const int c = wid * 2 + i;
      #pragma unroll
      for (int t = 0; t < 4; ++t) {
        PKu pk; pk.u4 = pkreg[i][t];
        #pragma unroll
        for (int nf = 0; nf < 4; ++nf) {
          const unsigned short* vp = vpanel + (size_t)(nf * 16 + l15) * MTOT
                                   + c * 128 + (((t * 4 + lg) ^ l15)) * 8;
          f16x8 bv = *(const f16x8*)vp;
          pv[nf] = MFMAH16(pk.h8, bv, pv[nf]);
        }
      }
    }

    // ---- phase c: emit rows 2*wid, 2*wid+1 (8KB contiguous, NT) ----
    #pragma unroll
    for (int i = 0; i < 2; ++i) {
      const int r = wid * 2 + i;
      const float invr = __shfl(inv, r, 64);
      float* orow = out + (panrow0 + q0 + r) * SEQ;
      #pragma unroll
      for (int g = 0; g < 8; ++g) {
        const int o = g * 512 + lane * 8;             // logical byte in fp16 row
        const int ph = o ^ ((r & 15) << 4);           // storage swizzle
        uint2 w2 = *(const uint2*)((const char*)P + r * 4096 + ph);
        f32x4 ov;
        ov[0] = h2f((unsigned short)(w2.x & 0xffff)) * invr;
        ov[1] = h2f((unsigned short)(w2.x >> 16)) * invr;
        ov[2] = h2f((unsigned short)(w2.y & 0xffff)) * invr;
        ov[3] = h2f((unsigned short)(w2.y >> 16)) * invr;
        __builtin_nontemporal_store(ov, (f32x4*)(orow + (o >> 1)));
      }
    }

    asm volatile("s_waitcnt lgkmcnt(0)" ::: "memory");
    __builtin_amdgcn_s_barrier();             // bar2: emit reads done, P dead
    __builtin_amdgcn_sched_barrier(0);

    // ---- phase d: cross-wave PV reduce through P area (stride 68 floats) ----
    float* pvred = (float*)P;
    #pragma unroll
    for (int nf = 0; nf < 4; ++nf)
      #pragma unroll
      for (int e = 0; e < 4; ++e)
        pvred[(wid * 16 + (4 * lg + e)) * 68 + nf * 16 + l15] = pv[nf][e];

    asm volatile("s_waitcnt lgkmcnt(0)" ::: "memory");
    __builtin_amdgcn_s_barrier();             // bar3: partials visible
    __builtin_amdgcn_sched_barrier(0);

    #pragma unroll
    for (int i = 0; i < 2; ++i) {
      const int r = wid * 2 + i;
      const float invr = __shfl(inv, r, 64);
      float v = 0.f;
      #pragma unroll
      for (int w2 = 0; w2 < 8; ++w2)
        v += pvred[(w2 * 16 + r) * 68 + lane];
      __builtin_nontemporal_store(v * invr, avbase + (panrow0 + q0 + r) * HDIM + lane);
    }

    asm volatile("s_waitcnt lgkmcnt(0)" ::: "memory");
    __builtin_amdgcn_s_barrier();             // bar4: reduce reads done before next tile
    __builtin_amdgcn_sched_barrier(0);
  }
}

extern "C" void kernel_launch(void* const* d_in, const int* in_sizes, int n_in,
                              void* d_out, int out_size, void* d_ws, size_t ws_size,
                              hipStream_t stream)
{
  const float* x  = (const float*)d_in[0];
  const float* wq = (const float*)d_in[1];
  const float* wk = (const float*)d_in[2];
  const float* wv = (const float*)d_in[3];
  float* out = (float*)d_out;
  unsigned short* ws = (unsigned short*)d_ws;

  unsigned short* xb  = ws;
  unsigned short* wqb = ws + 4194304;
  unsigned short* wkb = ws + 5242880;
  unsigned short* wvb = ws + 6291456;
  unsigned short* Qb  = ws + 7340032;
  unsigned short* Kb  = ws + 11534336;
  unsigned short* Vt  = ws + 15728640;   // fp16

  cvt_bf16<<<7168, 256, 0, stream>>>(x, wq, wk, wv, ws);
  qkv_gemm<<<dim3(8, 32, 3), 256, 0, stream>>>(xb, wqb, wkb, wvb, Qb, Kb, Vt);
  attn_all<<<512, 512, 0, stream>>>(Qb, Kb, Vt, out);
}

// Round 11
// 210.130 us; speedup vs baseline: 1.1360x; 1.1360x over previous
//
#include <hip/hip_runtime.h>
#include <hip/hip_bf16.h>
#include <stdint.h>
#include <stddef.h>

#define NB 2
#define SEQ 2048
#define HIDN 1024
#define NHEAD 16
#define HDIM 64
#define MTOT (NB * SEQ)   // 4096

typedef short bf16x8 __attribute__((ext_vector_type(8)));
typedef _Float16 f16x8 __attribute__((ext_vector_type(8)));
typedef __fp16 h16x2 __attribute__((ext_vector_type(2)));
typedef float f32x4 __attribute__((ext_vector_type(4)));
typedef uint32_t u32x4 __attribute__((ext_vector_type(4)));

#define MFMA16(a, b, c)  __builtin_amdgcn_mfma_f32_16x16x32_bf16(a, b, c, 0, 0, 0)
#define MFMAH16(a, b, c) __builtin_amdgcn_mfma_f32_16x16x32_f16(a, b, c, 0, 0, 0)

__device__ __forceinline__ unsigned short f2bf(float f) {
  union { float f; uint32_t u; } v; v.f = f;
  uint32_t u = v.u;
  uint32_t r = (u + 0x7fffu + ((u >> 16) & 1u)) >> 16;
  return (unsigned short)r;
}

__device__ __forceinline__ unsigned short f2h(float f) {
  _Float16 h = (_Float16)f;
  return *reinterpret_cast<unsigned short*>(&h);
}

__device__ __forceinline__ float h2f(unsigned short u) {
  _Float16 h = *reinterpret_cast<_Float16*>(&u);
  return (float)h;
}

__device__ __forceinline__ void gload16(const void* g, void* l) {
  __builtin_amdgcn_global_load_lds((const __attribute__((address_space(1))) void*)g,
                                   (__attribute__((address_space(3))) void*)l,
                                   16, 0, 0);
}

// ---------------- kernel 1: fp32 -> bf16 conversion ----------------
__global__ void cvt_bf16(const float* __restrict__ x, const float* __restrict__ wq,
                         const float* __restrict__ wk, const float* __restrict__ wv,
                         unsigned short* __restrict__ dst)
{
  size_t i4 = ((size_t)blockIdx.x * blockDim.x + threadIdx.x) * 4;
  const float* s; size_t off;
  if (i4 < 4194304UL)      { s = x;  off = i4; }
  else if (i4 < 5242880UL) { s = wq; off = i4 - 4194304UL; }
  else if (i4 < 6291456UL) { s = wk; off = i4 - 5242880UL; }
  else                     { s = wv; off = i4 - 6291456UL; }
  float4 v = *(const float4*)(s + off);
  ushort4 o;
  o.x = f2bf(v.x); o.y = f2bf(v.y); o.z = f2bf(v.z); o.w = f2bf(v.w);
  *(ushort4*)(dst + i4) = o;
}

// ---------------- kernel 2: QKV projection GEMM (double-buffered) ----------
// z=0: Qb bf16 (plain).
// z=1: Kb bf16, row-permuted + column-XOR-swizzled (16B slots) per head strip.
// z=2: Vt fp16 transposed [d][token], token-slot XOR-swizzled per 128-token seg.
__global__ __launch_bounds__(256, 2) void qkv_gemm(
    const unsigned short* __restrict__ xb,
    const unsigned short* __restrict__ wqb,
    const unsigned short* __restrict__ wkb,
    const unsigned short* __restrict__ wvb,
    unsigned short* __restrict__ Qb,
    unsigned short* __restrict__ Kb,
    unsigned short* __restrict__ Vt)
{
  __shared__ unsigned short As[2][128 * 64];   // 16KB each
  __shared__ unsigned short Bs[2][128 * 64];

  const int z = blockIdx.z;
  const unsigned short* W = (z == 0) ? wqb : (z == 1) ? wkb : wvb;
  const int n0 = blockIdx.x * 128;
  const int m0 = blockIdx.y * 128;
  const int tid = threadIdx.x;
  const int lane = tid & 63;
  const int wid = tid >> 6;
  const int l15 = lane & 15;
  const int lg = lane >> 4;

  f32x4 acc[4][4] = {};

  const int wr = (wid >> 1) * 64;
  const int wc = (wid & 1) * 64;

  #define QSTAGE(buf, kt) { \
    _Pragma("unroll") \
    for (int i = 0; i < 4; ++i) { \
      int row = wid * 32 + i * 8 + (lane >> 3); \
      int chunk = (lane & 7) ^ (row & 7); \
      const unsigned short* ga = xb + (size_t)(m0 + row) * HIDN + (kt) * 64 + chunk * 8; \
      const unsigned short* gb = W  + (size_t)(n0 + row) * HIDN + (kt) * 64 + chunk * 8; \
      gload16(ga, (char*)As[buf] + wid * 4096 + i * 1024); \
      gload16(gb, (char*)Bs[buf] + wid * 4096 + i * 1024); \
    } }

  QSTAGE(0, 0)
  __builtin_amdgcn_sched_barrier(0);
  asm volatile("s_waitcnt vmcnt(0) lgkmcnt(0)" ::: "memory");
  __builtin_amdgcn_s_barrier();
  __builtin_amdgcn_sched_barrier(0);

  for (int kt = 0; kt < 16; ++kt) {
    const int cur = kt & 1;
    if (kt < 15) QSTAGE(cur ^ 1, kt + 1)
    __builtin_amdgcn_sched_barrier(0);

    #pragma unroll
    for (int ks = 0; ks < 2; ++ks) {
      bf16x8 af[4], bfr[4];
      #pragma unroll
      for (int mi = 0; mi < 4; ++mi) {
        int row = wr + mi * 16 + l15;
        int cb = (ks * 64 + lg * 16) ^ ((row & 7) << 4);
        af[mi] = *(const bf16x8*)((const char*)As[cur] + row * 128 + cb);
      }
      #pragma unroll
      for (int ni = 0; ni < 4; ++ni) {
        int row = wc + ni * 16 + l15;
        int cb = (ks * 64 + lg * 16) ^ ((row & 7) << 4);
        bfr[ni] = *(const bf16x8*)((const char*)Bs[cur] + row * 128 + cb);
      }
      #pragma unroll
      for (int mi = 0; mi < 4; ++mi)
        #pragma unroll
        for (int ni = 0; ni < 4; ++ni)
          acc[mi][ni] = MFMA16(af[mi], bfr[ni], acc[mi][ni]);
    }

    __builtin_amdgcn_sched_barrier(0);
    asm volatile("s_waitcnt vmcnt(0) lgkmcnt(0)" ::: "memory");
    __builtin_amdgcn_s_barrier();
    __builtin_amdgcn_sched_barrier(0);
  }
  #undef QSTAGE

  if (z < 2) {
    unsigned short* O = (z == 0) ? Qb : Kb;
    #pragma unroll
    for (int mi = 0; mi < 4; ++mi)
      #pragma unroll
      for (int ni = 0; ni < 4; ++ni) {
        int n = n0 + wc + ni * 16 + l15;
        #pragma unroll
        for (int e = 0; e < 4; ++e) {
          int m = m0 + wr + mi * 16 + lg * 4 + e;
          if (z == 0) {
            O[(size_t)m * HIDN + n] = f2bf(acc[mi][ni][e]);
          } else {
            int mm = (m & ~31) | (((m >> 2) & 1) << 4) | (((m >> 3) & 3) << 2) | (m & 3);
            int nn = (n & ~56) | (((((n >> 3) & 7) ^ (mm & 7))) << 3);
            O[(size_t)mm * HIDN + nn] = f2bf(acc[mi][ni][e]);
          }
        }
      }
  } else {
    #pragma unroll
    for (int mi = 0; mi < 4; ++mi)
      #pragma unroll
      for (int ni = 0; ni < 4; ++ni) {
        int n = n0 + wc + ni * 16 + l15;          // output channel d
        int m = m0 + wr + mi * 16 + lg * 4;        // token (mult of 4)
        int mmv = (m & ~120) | (((((m >> 3) & 15) ^ (n & 15))) << 3);
        ushort4 pk;
        pk.x = f2h(acc[mi][ni][0]);
        pk.y = f2h(acc[mi][ni][1]);
        pk.z = f2h(acc[mi][ni][2]);
        pk.w = f2h(acc[mi][ni][3]);
        *(ushort4*)(Vt + (size_t)n * MTOT + mmv) = pk;
      }
  }
}

// ---------------- kernel 3: attn_pv — sums + PV only, 48KB LDS, 3 blk/CU ---
// 512 threads = 8 waves, one (b,h) panel, 128 q-rows per block (16/wave).
// K single-buffered (16KB), V double-buffered (2x16KB). Per chunk:
// QK -> lgkm+barrier (Ks consumed) -> issue next K/V stage -> exp/pack (hides
// loads) -> PV from Vs[cur] -> vmcnt(0)+barrier.
__global__ __launch_bounds__(512, 6) void attn_pv(
    const unsigned short* __restrict__ Qb,
    const unsigned short* __restrict__ Kb,
    const unsigned short* __restrict__ Vt,
    float* __restrict__ invs,
    float* __restrict__ out)
{
  __shared__ unsigned short Ks[128 * 64];      // 16KB single
  __shared__ unsigned short Vs[2][64 * 128];   // 16KB each

  const int bid = blockIdx.x;            // 0..511
  const int xcd = bid & 7;
  const int rest = bid >> 3;             // 0..63
  const int pan = (rest & 3) * 8 + xcd;  // XCD-pinned (b,h) panel 0..31
  const int slab = rest >> 2;            // 0..15
  const int b = pan >> 4, h = pan & 15;
  const int tid = threadIdx.x;
  const int wid = tid >> 6;
  const int lane = tid & 63;
  const int l15 = lane & 15, lg = lane >> 4;
  const int q0 = slab * 128 + wid * 16;

  const unsigned short* qptr = Qb + ((size_t)(b * SEQ + q0 + l15) * HIDN + h * HDIM + lg * 8);
  const bf16x8 bq0 = *(const bf16x8*)qptr;
  const bf16x8 bq1 = *(const bf16x8*)(qptr + 32);

  const float C = 0.18033688011112042f;  // (1/8) * log2(e)

  const unsigned short* kpanel = Kb + (size_t)b * SEQ * HIDN + h * HDIM;
  const unsigned short* vpanel = Vt + (size_t)h * HDIM * MTOT + b * SEQ;

  #define STAGE_K(c) { \
    _Pragma("unroll") \
    for (int i = 0; i < 2; ++i) { \
      int row = wid * 8 + i * 64 + (lane >> 3); \
      const unsigned short* src = kpanel + (size_t)((c) * 128 + row) * HIDN + (lane & 7) * 8; \
      gload16(src, (char*)Ks + wid * 1024 + i * 8192); \
    } }
  #define STAGE_V(buf, c) { \
    _Pragma("unroll") \
    for (int i = 0; i < 2; ++i) { \
      int dl = wid * 4 + i * 32 + (lane >> 4); \
      const unsigned short* src = vpanel + (size_t)dl * MTOT + (c) * 128 + (lane & 15) * 8; \
      gload16(src, (char*)Vs[buf] + wid * 1024 + i * 8192); \
    } }

  STAGE_K(0); STAGE_V(0, 0);
  __builtin_amdgcn_sched_barrier(0);
  asm volatile("s_waitcnt vmcnt(0) lgkmcnt(0)" ::: "memory");
  __builtin_amdgcn_s_barrier();
  __builtin_amdgcn_sched_barrier(0);

  float sm = 0.f;
  f32x4 pv[4] = {};

  for (int c = 0; c < 16; ++c) {
    const int cur = c & 1;

    // QK^T from Ks (swizzled reads)
    f32x4 acc[8] = {};
    #pragma unroll
    for (int kf = 0; kf < 8; ++kf) {
      const int rowL = kf * 16 + l15;
      const char* kr = (const char*)Ks + rowL * 128;
      bf16x8 a0 = *(const bf16x8*)(kr + ((lg    ) ^ (rowL & 7)) * 16);
      bf16x8 a1 = *(const bf16x8*)(kr + ((lg + 4) ^ (rowL & 7)) * 16);
      acc[kf] = MFMA16(a0, bq0, acc[kf]);
      acc[kf] = MFMA16(a1, bq1, acc[kf]);
    }

    // all waves done reading Ks -> safe to restage it
    __builtin_amdgcn_sched_barrier(0);
    asm volatile("s_waitcnt lgkmcnt(0)" ::: "memory");
    __builtin_amdgcn_s_barrier();
    __builtin_amdgcn_sched_barrier(0);

    if (c < 15) { STAGE_K(c + 1); STAGE_V(cur ^ 1, c + 1); }
    __builtin_amdgcn_sched_barrier(0);

    // exp + pack + sum (VALU, overlaps the staging loads) + PV
    #pragma unroll
    for (int t = 0; t < 4; ++t) {
      float4 s0, s1;
      s0.x = exp2f(acc[2 * t][0] * C);
      s0.y = exp2f(acc[2 * t][1] * C);
      s0.z = exp2f(acc[2 * t][2] * C);
      s0.w = exp2f(acc[2 * t][3] * C);
      s1.x = exp2f(acc[2 * t + 1][0] * C);
      s1.y = exp2f(acc[2 * t + 1][1] * C);
      s1.z = exp2f(acc[2 * t + 1][2] * C);
      s1.w = exp2f(acc[2 * t + 1][3] * C);
      sm += ((s0.x + s0.y) + (s0.z + s0.w)) + ((s1.x + s1.y) + (s1.z + s1.w));

      union PKu { h16x2 h2[4]; f16x8 h8; } pk;
      pk.h2[0] = __builtin_amdgcn_cvt_pkrtz(s0.x, s0.y);
      pk.h2[1] = __builtin_amdgcn_cvt_pkrtz(s0.z, s0.w);
      pk.h2[2] = __builtin_amdgcn_cvt_pkrtz(s1.x, s1.y);
      pk.h2[3] = __builtin_amdgcn_cvt_pkrtz(s1.z, s1.w);

      #pragma unroll
      for (int nf = 0; nf < 4; ++nf) {
        const int d = nf * 16 + l15;
        f16x8 bv = *(const f16x8*)((const char*)Vs[cur] + d * 256 + (((t * 4 + lg) ^ l15)) * 16);
        pv[nf] = MFMAH16(pk.h8, bv, pv[nf]);
      }
    }

    // stages complete & visible for next chunk; Vs[cur] fully consumed
    __builtin_amdgcn_sched_barrier(0);
    asm volatile("s_waitcnt vmcnt(0) lgkmcnt(0)" ::: "memory");
    __builtin_amdgcn_s_barrier();
    __builtin_amdgcn_sched_barrier(0);
  }

  // row sums -> inverses (lane-local: q = l15)
  #pragma unroll
  for (int off = 16; off <= 32; off <<= 1) sm += __shfl_xor(sm, off, 64);
  const float inv = __builtin_amdgcn_rcpf(sm);
  if (lane < 16) invs[(size_t)(b * NHEAD + h) * SEQ + q0 + lane] = inv;

  // attv: scale unnormalized PV by inv(q)
  float* av = out + (size_t)NB * NHEAD * SEQ * SEQ
            + ((size_t)(b * NHEAD + h) * SEQ + q0 + 4 * lg) * HDIM + l15;
  #pragma unroll
  for (int e = 0; e < 4; ++e) {
    const float invq = __shfl(inv, 4 * lg + e, 64);
    #pragma unroll
    for (int nf = 0; nf < 4; ++nf)
      __builtin_nontemporal_store(pv[nf][e] * invq, av + (size_t)e * HDIM + nf * 16);
  }
  #undef STAGE_K
  #undef STAGE_V
}

// ---------------- kernel 4: score_emit — recompute QK, row-contiguous fp32 -
// 512 threads = 8 waves; block owns 8 consecutive 16-row q-tiles of a panel.
// Phase 1: each wave computes 2 key-chunks (K direct from L2, swizzle-decoded),
// exp, packs unnormalized fp16 P into XOR-swizzled LDS (16 rows x 2048).
// Phase 2: each wave emits 2 FULL rows: ds_read -> fp32 * inv -> 8KB-
// contiguous NT stores. vmcnt (stores) is NEVER waited on.
__global__ __launch_bounds__(512, 2) void score_emit(
    const unsigned short* __restrict__ Qb,
    const unsigned short* __restrict__ Kb,
    const float* __restrict__ invs,
    float* __restrict__ out)
{
  __shared__ unsigned short P[16 * 2048];   // 64KB

  const int bid = blockIdx.x;            // 0..511
  const int xcd = bid & 7;
  const int rest = bid >> 3;             // 0..63
  const int pan = (rest & 3) * 8 + xcd;  // XCD-pinned (b,h) panel 0..31
  const int blkp = rest >> 2;            // 0..15 block-within-panel
  const int b = pan >> 4, h = pan & 15;
  const int tid = threadIdx.x;
  const int wid = tid >> 6;
  const int lane = tid & 63;
  const int l15 = lane & 15, lg = lane >> 4;

  const float C = 0.18033688011112042f;
  const unsigned short* kpanel = Kb + (size_t)b * SEQ * HIDN + h * HDIM;
  const size_t panrow0 = (size_t)(b * NHEAD + h) * SEQ;

  for (int tt = 0; tt < 8; ++tt) {
    const int q0 = (blkp * 8 + tt) * 16;

    const unsigned short* qptr = Qb + ((size_t)(b * SEQ + q0 + l15) * HIDN + h * HDIM + lg * 8);
    const bf16x8 bq0 = *(const bf16x8*)qptr;
    const bf16x8 bq1 = *(const bf16x8*)(qptr + 32);

    // ---- phase 1: compute 2 chunks, pack into LDS ----
    #pragma unroll
    for (int i = 0; i < 2; ++i) {
      const int c = wid * 2 + i;
      f32x4 acc[8] = {};
      #pragma unroll
      for (int kf = 0; kf < 8; ++kf) {
        const int s = c * 128 + kf * 16 + l15;     // storage row
        const unsigned short* kr = kpanel + (size_t)s * HIDN;
        bf16x8 a0 = *(const bf16x8*)(kr + ((lg      ^ (s & 7))) * 8);
        bf16x8 a1 = *(const bf16x8*)(kr + (((lg + 4) ^ (s & 7))) * 8);
        acc[kf] = MFMA16(a0, bq0, acc[kf]);
        acc[kf] = MFMA16(a1, bq1, acc[kf]);
      }
      #pragma unroll
      for (int t = 0; t < 4; ++t) {
        float4 s0, s1;
        s0.x = exp2f(acc[2 * t][0] * C);
        s0.y = exp2f(acc[2 * t][1] * C);
        s0.z = exp2f(acc[2 * t][2] * C);
        s0.w = exp2f(acc[2 * t][3] * C);
        s1.x = exp2f(acc[2 * t + 1][0] * C);
        s1.y = exp2f(acc[2 * t + 1][1] * C);
        s1.z = exp2f(acc[2 * t + 1][2] * C);
        s1.w = exp2f(acc[2 * t + 1][3] * C);

        union PKu { h16x2 h2[4]; u32x4 u4; } pk;
        pk.h2[0] = __builtin_amdgcn_cvt_pkrtz(s0.x, s0.y);
        pk.h2[1] = __builtin_amdgcn_cvt_pkrtz(s0.z, s0.w);
        pk.h2[2] = __builtin_amdgcn_cvt_pkrtz(s1.x, s1.y);
        pk.h2[3] = __builtin_amdgcn_cvt_pkrtz(s1.z, s1.w);

        const int off = c * 256 + ((((t * 4 + lg) ^ l15)) << 4);
        *(u32x4*)((char*)P + l15 * 4096 + off) = pk.u4;
      }
    }

    asm volatile("s_waitcnt lgkmcnt(0)" ::: "memory");
    __builtin_amdgcn_s_barrier();
    __builtin_amdgcn_sched_barrier(0);

    // ---- phase 2: emit rows 2*wid, 2*wid+1 (8KB contiguous each) ----
    #pragma unroll
    for (int i = 0; i < 2; ++i) {
      const int r = wid * 2 + i;
      const float invr = invs[panrow0 + q0 + r];
      float* orow = out + (panrow0 + q0 + r) * SEQ;
      #pragma unroll
      for (int g = 0; g < 8; ++g) {
        const int o = g * 512 + lane * 8;             // logical byte in row
        const int ph = o ^ ((r & 15) << 4);           // swizzled
        uint2 w = *(const uint2*)((const char*)P + r * 4096 + ph);
        f32x4 ov;
        ov[0] = h2f((unsigned short)(w.x & 0xffff)) * invr;
        ov[1] = h2f((unsigned short)(w.x >> 16)) * invr;
        ov[2] = h2f((unsigned short)(w.y & 0xffff)) * invr;
        ov[3] = h2f((unsigned short)(w.y >> 16)) * invr;
        __builtin_nontemporal_store(ov, (f32x4*)(orow + (o >> 1)));
      }
    }

    asm volatile("s_waitcnt lgkmcnt(0)" ::: "memory");
    __builtin_amdgcn_s_barrier();
    __builtin_amdgcn_sched_barrier(0);
  }
}

extern "C" void kernel_launch(void* const* d_in, const int* in_sizes, int n_in,
                              void* d_out, int out_size, void* d_ws, size_t ws_size,
                              hipStream_t stream)
{
  const float* x  = (const float*)d_in[0];
  const float* wq = (const float*)d_in[1];
  const float* wk = (const float*)d_in[2];
  const float* wv = (const float*)d_in[3];
  float* out = (float*)d_out;
  unsigned short* ws = (unsigned short*)d_ws;

  unsigned short* xb  = ws;              // dead after qkv; invs aliases it
  unsigned short* wqb = ws + 4194304;
  unsigned short* wkb = ws + 5242880;
  unsigned short* wvb = ws + 6291456;
  unsigned short* Qb  = ws + 7340032;
  unsigned short* Kb  = ws + 11534336;
  unsigned short* Vt  = ws + 15728640;   // fp16
  float* invs = (float*)ws;              // 256KB, aliases dead xb

  cvt_bf16<<<7168, 256, 0, stream>>>(x, wq, wk, wv, ws);
  qkv_gemm<<<dim3(8, 32, 3), 256, 0, stream>>>(xb, wqb, wkb, wvb, Qb, Kb, Vt);
  attn_pv<<<512, 512, 0, stream>>>(Qb, Kb, Vt, invs, out);
  score_emit<<<512, 512, 0, stream>>>(Qb, Kb, invs, out);
}

// Round 12
// 199.885 us; speedup vs baseline: 1.1942x; 1.0513x over previous
//
#include <hip/hip_runtime.h>
#include <hip/hip_bf16.h>
#include <stdint.h>
#include <stddef.h>

#define NB 2
#define SEQ 2048
#define HIDN 1024
#define NHEAD 16
#define HDIM 64
#define MTOT (NB * SEQ)   // 4096

typedef short bf16x8 __attribute__((ext_vector_type(8)));
typedef _Float16 f16x8 __attribute__((ext_vector_type(8)));
typedef __fp16 h16x2 __attribute__((ext_vector_type(2)));
typedef float f32x4 __attribute__((ext_vector_type(4)));
typedef uint32_t u32x4 __attribute__((ext_vector_type(4)));

#define MFMA16(a, b, c)  __builtin_amdgcn_mfma_f32_16x16x32_bf16(a, b, c, 0, 0, 0)
#define MFMAH16(a, b, c) __builtin_amdgcn_mfma_f32_16x16x32_f16(a, b, c, 0, 0, 0)

__device__ __forceinline__ unsigned short f2bf(float f) {
  union { float f; uint32_t u; } v; v.f = f;
  uint32_t u = v.u;
  uint32_t r = (u + 0x7fffu + ((u >> 16) & 1u)) >> 16;
  return (unsigned short)r;
}

__device__ __forceinline__ unsigned short f2h(float f) {
  _Float16 h = (_Float16)f;
  return *reinterpret_cast<unsigned short*>(&h);
}

__device__ __forceinline__ float h2f(unsigned short u) {
  _Float16 h = *reinterpret_cast<_Float16*>(&u);
  return (float)h;
}

__device__ __forceinline__ void gload16(const void* g, void* l) {
  __builtin_amdgcn_global_load_lds((const __attribute__((address_space(1))) void*)g,
                                   (__attribute__((address_space(3))) void*)l,
                                   16, 0, 0);
}

// ---------------- kernel 1: fp32 -> bf16 conversion ----------------
__global__ void cvt_bf16(const float* __restrict__ x, const float* __restrict__ wq,
                         const float* __restrict__ wk, const float* __restrict__ wv,
                         unsigned short* __restrict__ dst)
{
  size_t i4 = ((size_t)blockIdx.x * blockDim.x + threadIdx.x) * 4;
  const float* s; size_t off;
  if (i4 < 4194304UL)      { s = x;  off = i4; }
  else if (i4 < 5242880UL) { s = wq; off = i4 - 4194304UL; }
  else if (i4 < 6291456UL) { s = wk; off = i4 - 5242880UL; }
  else                     { s = wv; off = i4 - 6291456UL; }
  float4 v = *(const float4*)(s + off);
  ushort4 o;
  o.x = f2bf(v.x); o.y = f2bf(v.y); o.z = f2bf(v.z); o.w = f2bf(v.w);
  *(ushort4*)(dst + i4) = o;
}

// ---------------- kernel 2: QKV projection GEMM (round-9 exact) ------------
// z=0: Qb bf16 (plain).
// z=1: Kb bf16, row-permuted + column-XOR-swizzled (16B slots) per head strip.
// z=2: Vt fp16 transposed [d][token], token-slot XOR-swizzled per 128-token seg.
__global__ __launch_bounds__(256, 2) void qkv_gemm(
    const unsigned short* __restrict__ xb,
    const unsigned short* __restrict__ wqb,
    const unsigned short* __restrict__ wkb,
    const unsigned short* __restrict__ wvb,
    unsigned short* __restrict__ Qb,
    unsigned short* __restrict__ Kb,
    unsigned short* __restrict__ Vt)
{
  __shared__ unsigned short As[128 * 64];
  __shared__ unsigned short Bs[128 * 64];

  const int z = blockIdx.z;
  const unsigned short* W = (z == 0) ? wqb : (z == 1) ? wkb : wvb;
  const int n0 = blockIdx.x * 128;
  const int m0 = blockIdx.y * 128;
  const int tid = threadIdx.x;
  const int lane = tid & 63;
  const int wid = tid >> 6;
  const int l15 = lane & 15;
  const int lg = lane >> 4;

  f32x4 acc[4][4] = {};

  const int wr = (wid >> 1) * 64;
  const int wc = (wid & 1) * 64;

  for (int kt = 0; kt < 16; ++kt) {
    __syncthreads();
    #pragma unroll
    for (int i = 0; i < 4; ++i) {
      int row = wid * 32 + i * 8 + (lane >> 3);
      int chunk = (lane & 7) ^ (row & 7);
      const unsigned short* ga = xb + (size_t)(m0 + row) * HIDN + kt * 64 + chunk * 8;
      const unsigned short* gb = W  + (size_t)(n0 + row) * HIDN + kt * 64 + chunk * 8;
      gload16(ga, (char*)As + wid * 4096 + i * 1024);
      gload16(gb, (char*)Bs + wid * 4096 + i * 1024);
    }
    __syncthreads();

    #pragma unroll
    for (int ks = 0; ks < 2; ++ks) {
      bf16x8 af[4], bfr[4];
      #pragma unroll
      for (int mi = 0; mi < 4; ++mi) {
        int row = wr + mi * 16 + l15;
        int cb = (ks * 64 + lg * 16) ^ ((row & 7) << 4);
        af[mi] = *(const bf16x8*)((const char*)As + row * 128 + cb);
      }
      #pragma unroll
      for (int ni = 0; ni < 4; ++ni) {
        int row = wc + ni * 16 + l15;
        int cb = (ks * 64 + lg * 16) ^ ((row & 7) << 4);
        bfr[ni] = *(const bf16x8*)((const char*)Bs + row * 128 + cb);
      }
      #pragma unroll
      for (int mi = 0; mi < 4; ++mi)
        #pragma unroll
        for (int ni = 0; ni < 4; ++ni)
          acc[mi][ni] = MFMA16(af[mi], bfr[ni], acc[mi][ni]);
    }
  }

  if (z < 2) {
    unsigned short* O = (z == 0) ? Qb : Kb;
    #pragma unroll
    for (int mi = 0; mi < 4; ++mi)
      #pragma unroll
      for (int ni = 0; ni < 4; ++ni) {
        int n = n0 + wc + ni * 16 + l15;
        #pragma unroll
        for (int e = 0; e < 4; ++e) {
          int m = m0 + wr + mi * 16 + lg * 4 + e;
          if (z == 0) {
            O[(size_t)m * HIDN + n] = f2bf(acc[mi][ni][e]);
          } else {
            int mm = (m & ~31) | (((m >> 2) & 1) << 4) | (((m >> 3) & 3) << 2) | (m & 3);
            int nn = (n & ~56) | (((((n >> 3) & 7) ^ (mm & 7))) << 3);
            O[(size_t)mm * HIDN + nn] = f2bf(acc[mi][ni][e]);
          }
        }
      }
  } else {
    #pragma unroll
    for (int mi = 0; mi < 4; ++mi)
      #pragma unroll
      for (int ni = 0; ni < 4; ++ni) {
        int n = n0 + wc + ni * 16 + l15;          // output channel d
        int m = m0 + wr + mi * 16 + lg * 4;        // token (mult of 4)
        int mmv = (m & ~120) | (((((m >> 3) & 15) ^ (n & 15))) << 3);
        ushort4 pk;
        pk.x = f2h(acc[mi][ni][0]);
        pk.y = f2h(acc[mi][ni][1]);
        pk.z = f2h(acc[mi][ni][2]);
        pk.w = f2h(acc[mi][ni][3]);
        *(ushort4*)(Vt + (size_t)n * MTOT + mmv) = pk;
      }
  }
}

// ---------------- kernel 3: attn_split — pv and emit co-scheduled ----------
// 1024 blocks x 512 threads. Block type alternates every 8 blocks (preserves
// XCD pinning for both types). type 0 = pv (sums+PV+attv, round-9 attn_pv,
// self-contained inv); type 1 = emit (recompute QK, OWN row sums, emit
// 8KB-contiguous normalized fp32 rows; stores never vmcnt-gated).
__global__ __launch_bounds__(512, 2) void attn_split(
    const unsigned short* __restrict__ Qb,
    const unsigned short* __restrict__ Kb,
    const unsigned short* __restrict__ Vt,
    float* __restrict__ out)
{
  __shared__ char smem[66048];   // pv: 64KB (Ks2+Vs2). emit: 64KB P + 512B sums.

  const int bid = blockIdx.x;            // 0..1023
  const int gg = bid >> 3;
  const int type = gg & 1;
  const int s = (bid & 7) | ((gg >> 1) << 3);   // 0..511, s%8 == bid%8 (XCD)

  const int xcd = s & 7;
  const int rest = s >> 3;               // 0..63
  const int pan = (rest & 3) * 8 + xcd;  // XCD-pinned (b,h) panel 0..31
  const int b = pan >> 4, h = pan & 15;
  const int tid = threadIdx.x;
  const int wid = tid >> 6;
  const int lane = tid & 63;
  const int l15 = lane & 15, lg = lane >> 4;

  const float C = 0.18033688011112042f;  // (1/8) * log2(e)
  const unsigned short* kpanel = Kb + (size_t)b * SEQ * HIDN + h * HDIM;
  const size_t panrow0 = (size_t)(b * NHEAD + h) * SEQ;

  if (type == 0) {
    // ================= pv: sums + PV + attv (round-9 attn_pv) =================
    const int slab = rest >> 2;          // 0..15
    const int q0 = slab * 128 + wid * 16;

    const unsigned short* qptr = Qb + ((size_t)(b * SEQ + q0 + l15) * HIDN + h * HDIM + lg * 8);
    const bf16x8 bq0 = *(const bf16x8*)qptr;
    const bf16x8 bq1 = *(const bf16x8*)(qptr + 32);
    const unsigned short* vpanel = Vt + (size_t)h * HDIM * MTOT + b * SEQ;

    #define STAGE_K(buf, c) { \
      _Pragma("unroll") \
      for (int i = 0; i < 2; ++i) { \
        int row = wid * 8 + i * 64 + (lane >> 3); \
        const unsigned short* src = kpanel + (size_t)((c) * 128 + row) * HIDN + (lane & 7) * 8; \
        gload16(src, smem + (buf) * 16384 + wid * 1024 + i * 8192); \
      } }
    #define STAGE_V(buf, c) { \
      _Pragma("unroll") \
      for (int i = 0; i < 2; ++i) { \
        int dl = wid * 4 + i * 32 + (lane >> 4); \
        const unsigned short* src = vpanel + (size_t)dl * MTOT + (c) * 128 + (lane & 15) * 8; \
        gload16(src, smem + 32768 + (buf) * 16384 + wid * 1024 + i * 8192); \
      } }

    STAGE_K(0, 0); STAGE_V(0, 0);
    __builtin_amdgcn_sched_barrier(0);
    asm volatile("s_waitcnt vmcnt(0)" ::: "memory");
    __builtin_amdgcn_s_barrier();
    __builtin_amdgcn_sched_barrier(0);

    float sm = 0.f;
    f32x4 pv[4] = {};

    for (int c = 0; c < 16; ++c) {
      const int cur = c & 1;
      if (c < 15) { STAGE_K(cur ^ 1, c + 1); STAGE_V(cur ^ 1, c + 1); }
      __builtin_amdgcn_sched_barrier(0);

      f32x4 acc[8] = {};
      #pragma unroll
      for (int kf = 0; kf < 8; ++kf) {
        const int rowL = kf * 16 + l15;
        const char* kr = smem + cur * 16384 + rowL * 128;
        bf16x8 a0 = *(const bf16x8*)(kr + ((lg    ) ^ (rowL & 7)) * 16);
        bf16x8 a1 = *(const bf16x8*)(kr + ((lg + 4) ^ (rowL & 7)) * 16);
        acc[kf] = MFMA16(a0, bq0, acc[kf]);
        acc[kf] = MFMA16(a1, bq1, acc[kf]);
      }

      #pragma unroll
      for (int t = 0; t < 4; ++t) {
        float4 s0, s1;
        s0.x = exp2f(acc[2 * t][0] * C);
        s0.y = exp2f(acc[2 * t][1] * C);
        s0.z = exp2f(acc[2 * t][2] * C);
        s0.w = exp2f(acc[2 * t][3] * C);
        s1.x = exp2f(acc[2 * t + 1][0] * C);
        s1.y = exp2f(acc[2 * t + 1][1] * C);
        s1.z = exp2f(acc[2 * t + 1][2] * C);
        s1.w = exp2f(acc[2 * t + 1][3] * C);
        sm += ((s0.x + s0.y) + (s0.z + s0.w)) + ((s1.x + s1.y) + (s1.z + s1.w));

        union PKu { h16x2 h2[4]; f16x8 h8; } pk;
        pk.h2[0] = __builtin_amdgcn_cvt_pkrtz(s0.x, s0.y);
        pk.h2[1] = __builtin_amdgcn_cvt_pkrtz(s0.z, s0.w);
        pk.h2[2] = __builtin_amdgcn_cvt_pkrtz(s1.x, s1.y);
        pk.h2[3] = __builtin_amdgcn_cvt_pkrtz(s1.z, s1.w);

        #pragma unroll
        for (int nf = 0; nf < 4; ++nf) {
          const int d = nf * 16 + l15;
          f16x8 bv = *(const f16x8*)(smem + 32768 + cur * 16384 + d * 256 + (((t * 4 + lg) ^ l15)) * 16);
          pv[nf] = MFMAH16(pk.h8, bv, pv[nf]);
        }
      }

      __builtin_amdgcn_sched_barrier(0);
      asm volatile("s_waitcnt vmcnt(0)" ::: "memory");
      __builtin_amdgcn_s_barrier();
      __builtin_amdgcn_sched_barrier(0);
    }

    #pragma unroll
    for (int off = 16; off <= 32; off <<= 1) sm += __shfl_xor(sm, off, 64);
    const float inv = __builtin_amdgcn_rcpf(sm);   // lane-local: q = l15

    float* av = out + (size_t)NB * NHEAD * SEQ * SEQ
              + (panrow0 + q0 + 4 * lg) * HDIM + l15;
    #pragma unroll
    for (int e = 0; e < 4; ++e) {
      const float invq = __shfl(inv, 4 * lg + e, 64);
      #pragma unroll
      for (int nf = 0; nf < 4; ++nf)
        __builtin_nontemporal_store(pv[nf][e] * invq, av + (size_t)e * HDIM + nf * 16);
    }
    #undef STAGE_K
    #undef STAGE_V

  } else {
    // ================= emit: recompute QK, own sums, contiguous rows ==========
    unsigned short* P = (unsigned short*)smem;      // 64KB
    float* sums = (float*)(smem + 65536);           // [8][16]
    const int blkp = rest >> 2;          // 0..15

    for (int tt = 0; tt < 8; ++tt) {
      const int q0 = (blkp * 8 + tt) * 16;

      const unsigned short* qptr = Qb + ((size_t)(b * SEQ + q0 + l15) * HIDN + h * HDIM + lg * 8);
      const bf16x8 bq0 = *(const bf16x8*)qptr;
      const bf16x8 bq1 = *(const bf16x8*)(qptr + 32);

      // ---- phase 1: compute 2 chunks, pack into LDS, partial sums ----
      float sm = 0.f;
      #pragma unroll
      for (int i = 0; i < 2; ++i) {
        const int c = wid * 2 + i;
        f32x4 acc[8] = {};
        #pragma unroll
        for (int kf = 0; kf < 8; ++kf) {
          const int sr = c * 128 + kf * 16 + l15;     // storage row
          const unsigned short* kr = kpanel + (size_t)sr * HIDN;
          bf16x8 a0 = *(const bf16x8*)(kr + ((lg      ^ (sr & 7))) * 8);
          bf16x8 a1 = *(const bf16x8*)(kr + (((lg + 4) ^ (sr & 7))) * 8);
          acc[kf] = MFMA16(a0, bq0, acc[kf]);
          acc[kf] = MFMA16(a1, bq1, acc[kf]);
        }
        #pragma unroll
        for (int t = 0; t < 4; ++t) {
          float4 s0, s1;
          s0.x = exp2f(acc[2 * t][0] * C);
          s0.y = exp2f(acc[2 * t][1] * C);
          s0.z = exp2f(acc[2 * t][2] * C);
          s0.w = exp2f(acc[2 * t][3] * C);
          s1.x = exp2f(acc[2 * t + 1][0] * C);
          s1.y = exp2f(acc[2 * t + 1][1] * C);
          s1.z = exp2f(acc[2 * t + 1][2] * C);
          s1.w = exp2f(acc[2 * t + 1][3] * C);
          sm += ((s0.x + s0.y) + (s0.z + s0.w)) + ((s1.x + s1.y) + (s1.z + s1.w));

          union PKu { h16x2 h2[4]; u32x4 u4; } pk;
          pk.h2[0] = __builtin_amdgcn_cvt_pkrtz(s0.x, s0.y);
          pk.h2[1] = __builtin_amdgcn_cvt_pkrtz(s0.z, s0.w);
          pk.h2[2] = __builtin_amdgcn_cvt_pkrtz(s1.x, s1.y);
          pk.h2[3] = __builtin_amdgcn_cvt_pkrtz(s1.z, s1.w);

          const int off = c * 256 + ((((t * 4 + lg) ^ l15)) << 4);
          *(u32x4*)((char*)P + l15 * 4096 + off) = pk.u4;
        }
      }
      sm += __shfl_xor(sm, 16, 64);
      sm += __shfl_xor(sm, 32, 64);
      if (lane < 16) sums[wid * 16 + lane] = sm;

      asm volatile("s_waitcnt lgkmcnt(0)" ::: "memory");
      __builtin_amdgcn_s_barrier();
      __builtin_amdgcn_sched_barrier(0);

      float tot = 0.f;
      #pragma unroll
      for (int w2 = 0; w2 < 8; ++w2) tot += sums[w2 * 16 + l15];
      const float inv = __builtin_amdgcn_rcpf(tot);

      // ---- phase 2: emit rows 2*wid, 2*wid+1 (8KB contiguous each) ----
      #pragma unroll
      for (int i = 0; i < 2; ++i) {
        const int r = wid * 2 + i;
        const float invr = __shfl(inv, r, 64);
        float* orow = out + (panrow0 + q0 + r) * SEQ;
        #pragma unroll
        for (int g = 0; g < 8; ++g) {
          const int o = g * 512 + lane * 8;             // logical byte in row
          const int ph = o ^ ((r & 15) << 4);           // swizzled
          uint2 w = *(const uint2*)((const char*)P + r * 4096 + ph);
          f32x4 ov;
          ov[0] = h2f((unsigned short)(w.x & 0xffff)) * invr;
          ov[1] = h2f((unsigned short)(w.x >> 16)) * invr;
          ov[2] = h2f((unsigned short)(w.y & 0xffff)) * invr;
          ov[3] = h2f((unsigned short)(w.y >> 16)) * invr;
          __builtin_nontemporal_store(ov, (f32x4*)(orow + (o >> 1)));
        }
      }

      asm volatile("s_waitcnt lgkmcnt(0)" ::: "memory");
      __builtin_amdgcn_s_barrier();
      __builtin_amdgcn_sched_barrier(0);
    }
  }
}

extern "C" void kernel_launch(void* const* d_in, const int* in_sizes, int n_in,
                              void* d_out, int out_size, void* d_ws, size_t ws_size,
                              hipStream_t stream)
{
  const float* x  = (const float*)d_in[0];
  const float* wq = (const float*)d_in[1];
  const float* wk = (const float*)d_in[2];
  const float* wv = (const float*)d_in[3];
  float* out = (float*)d_out;
  unsigned short* ws = (unsigned short*)d_ws;

  unsigned short* xb  = ws;
  unsigned short* wqb = ws + 4194304;
  unsigned short* wkb = ws + 5242880;
  unsigned short* wvb = ws + 6291456;
  unsigned short* Qb  = ws + 7340032;
  unsigned short* Kb  = ws + 11534336;
  unsigned short* Vt  = ws + 15728640;   // fp16

  cvt_bf16<<<7168, 256, 0, stream>>>(x, wq, wk, wv, ws);
  qkv_gemm<<<dim3(8, 32, 3), 256, 0, stream>>>(xb, wqb, wkb, wvb, Qb, Kb, Vt);
  attn_split<<<1024, 512, 0, stream>>>(Qb, Kb, Vt, out);
}

// Round 13
// 194.424 us; speedup vs baseline: 1.2277x; 1.0281x over previous
//
#include <hip/hip_runtime.h>
#include <hip/hip_bf16.h>
#include <stdint.h>
#include <stddef.h>

#define NB 2
#define SEQ 2048
#define HIDN 1024
#define NHEAD 16
#define HDIM 64
#define MTOT (NB * SEQ)   // 4096

typedef short bf16x8 __attribute__((ext_vector_type(8)));
typedef _Float16 f16x8 __attribute__((ext_vector_type(8)));
typedef __fp16 h16x2 __attribute__((ext_vector_type(2)));
typedef float f32x4 __attribute__((ext_vector_type(4)));
typedef uint32_t u32x4 __attribute__((ext_vector_type(4)));

#define MFMA16(a, b, c)  __builtin_amdgcn_mfma_f32_16x16x32_bf16(a, b, c, 0, 0, 0)
#define MFMAH16(a, b, c) __builtin_amdgcn_mfma_f32_16x16x32_f16(a, b, c, 0, 0, 0)

__device__ __forceinline__ unsigned short f2bf(float f) {
  union { float f; uint32_t u; } v; v.f = f;
  uint32_t u = v.u;
  uint32_t r = (u + 0x7fffu + ((u >> 16) & 1u)) >> 16;
  return (unsigned short)r;
}

__device__ __forceinline__ unsigned short f2h(float f) {
  _Float16 h = (_Float16)f;
  return *reinterpret_cast<unsigned short*>(&h);
}

__device__ __forceinline__ float h2f(unsigned short u) {
  _Float16 h = *reinterpret_cast<_Float16*>(&u);
  return (float)h;
}

__device__ __forceinline__ void gload16(const void* g, void* l) {
  __builtin_amdgcn_global_load_lds((const __attribute__((address_space(1))) void*)g,
                                   (__attribute__((address_space(3))) void*)l,
                                   16, 0, 0);
}

// ---------------- kernel 1: fp32 -> bf16 conversion ----------------
__global__ void cvt_bf16(const float* __restrict__ x, const float* __restrict__ wq,
                         const float* __restrict__ wk, const float* __restrict__ wv,
                         unsigned short* __restrict__ dst)
{
  size_t i4 = ((size_t)blockIdx.x * blockDim.x + threadIdx.x) * 4;
  const float* s; size_t off;
  if (i4 < 4194304UL)      { s = x;  off = i4; }
  else if (i4 < 5242880UL) { s = wq; off = i4 - 4194304UL; }
  else if (i4 < 6291456UL) { s = wk; off = i4 - 5242880UL; }
  else                     { s = wv; off = i4 - 6291456UL; }
  float4 v = *(const float4*)(s + off);
  ushort4 o;
  o.x = f2bf(v.x); o.y = f2bf(v.y); o.z = f2bf(v.z); o.w = f2bf(v.w);
  *(ushort4*)(dst + i4) = o;
}

// ---------------- kernel 2: QKV projection GEMM ----------------
// z=0: Qb bf16 (plain).
// z=1: Kb bf16, row-permuted + column-XOR-swizzled (16B slots) per head strip.
// z=2: Vt fp16 transposed [d][token], token-slot XOR-swizzled per 128-token seg.
// __launch_bounds__(256,3): 3 blocks/CU x 256 CU = 768 slots = grid size ->
// zero dispatch tail + 50% more cross-block TLP to hide staging.
__global__ __launch_bounds__(256, 3) void qkv_gemm(
    const unsigned short* __restrict__ xb,
    const unsigned short* __restrict__ wqb,
    const unsigned short* __restrict__ wkb,
    const unsigned short* __restrict__ wvb,
    unsigned short* __restrict__ Qb,
    unsigned short* __restrict__ Kb,
    unsigned short* __restrict__ Vt)
{
  __shared__ unsigned short As[128 * 64];
  __shared__ unsigned short Bs[128 * 64];

  const int z = blockIdx.z;
  const unsigned short* W = (z == 0) ? wqb : (z == 1) ? wkb : wvb;
  const int n0 = blockIdx.x * 128;
  const int m0 = blockIdx.y * 128;
  const int tid = threadIdx.x;
  const int lane = tid & 63;
  const int wid = tid >> 6;
  const int l15 = lane & 15;
  const int lg = lane >> 4;

  f32x4 acc[4][4] = {};

  const int wr = (wid >> 1) * 64;
  const int wc = (wid & 1) * 64;

  for (int kt = 0; kt < 16; ++kt) {
    __syncthreads();
    #pragma unroll
    for (int i = 0; i < 4; ++i) {
      int row = wid * 32 + i * 8 + (lane >> 3);
      int chunk = (lane & 7) ^ (row & 7);
      const unsigned short* ga = xb + (size_t)(m0 + row) * HIDN + kt * 64 + chunk * 8;
      const unsigned short* gb = W  + (size_t)(n0 + row) * HIDN + kt * 64 + chunk * 8;
      gload16(ga, (char*)As + wid * 4096 + i * 1024);
      gload16(gb, (char*)Bs + wid * 4096 + i * 1024);
    }
    __syncthreads();

    #pragma unroll
    for (int ks = 0; ks < 2; ++ks) {
      bf16x8 af[4], bfr[4];
      #pragma unroll
      for (int mi = 0; mi < 4; ++mi) {
        int row = wr + mi * 16 + l15;
        int cb = (ks * 64 + lg * 16) ^ ((row & 7) << 4);
        af[mi] = *(const bf16x8*)((const char*)As + row * 128 + cb);
      }
      #pragma unroll
      for (int ni = 0; ni < 4; ++ni) {
        int row = wc + ni * 16 + l15;
        int cb = (ks * 64 + lg * 16) ^ ((row & 7) << 4);
        bfr[ni] = *(const bf16x8*)((const char*)Bs + row * 128 + cb);
      }
      #pragma unroll
      for (int mi = 0; mi < 4; ++mi)
        #pragma unroll
        for (int ni = 0; ni < 4; ++ni)
          acc[mi][ni] = MFMA16(af[mi], bfr[ni], acc[mi][ni]);
    }
  }

  if (z < 2) {
    unsigned short* O = (z == 0) ? Qb : Kb;
    #pragma unroll
    for (int mi = 0; mi < 4; ++mi)
      #pragma unroll
      for (int ni = 0; ni < 4; ++ni) {
        int n = n0 + wc + ni * 16 + l15;
        #pragma unroll
        for (int e = 0; e < 4; ++e) {
          int m = m0 + wr + mi * 16 + lg * 4 + e;
          if (z == 0) {
            O[(size_t)m * HIDN + n] = f2bf(acc[mi][ni][e]);
          } else {
            int mm = (m & ~31) | (((m >> 2) & 1) << 4) | (((m >> 3) & 3) << 2) | (m & 3);
            int nn = (n & ~56) | (((((n >> 3) & 7) ^ (mm & 7))) << 3);
            O[(size_t)mm * HIDN + nn] = f2bf(acc[mi][ni][e]);
          }
        }
      }
  } else {
    #pragma unroll
    for (int mi = 0; mi < 4; ++mi)
      #pragma unroll
      for (int ni = 0; ni < 4; ++ni) {
        int n = n0 + wc + ni * 16 + l15;          // output channel d
        int m = m0 + wr + mi * 16 + lg * 4;        // token (mult of 4)
        int mmv = (m & ~120) | (((((m >> 3) & 15) ^ (n & 15))) << 3);
        ushort4 pk;
        pk.x = f2h(acc[mi][ni][0]);
        pk.y = f2h(acc[mi][ni][1]);
        pk.z = f2h(acc[mi][ni][2]);
        pk.w = f2h(acc[mi][ni][3]);
        *(ushort4*)(Vt + (size_t)n * MTOT + mmv) = pk;
      }
  }
}

// ---------------- kernel 3: attn_pv — sums + PV only, no score stores ------
// 512 threads = 8 waves, one (b,h) panel, 128 q-rows per block (16/wave).
// Single pass: QK^T, exp (no max), row-sums -> invs; PV with unnormalized
// fp16 P; attv scaled by inv at the end. Only ~16MB of stores total.
__global__ __launch_bounds__(512, 4) void attn_pv(
    const unsigned short* __restrict__ Qb,
    const unsigned short* __restrict__ Kb,
    const unsigned short* __restrict__ Vt,
    float* __restrict__ invs,
    float* __restrict__ out)
{
  __shared__ unsigned short Ks[2][128 * 64];   // 16KB each buf
  __shared__ unsigned short Vs[2][64 * 128];   // 16KB each buf

  const int bid = blockIdx.x;            // 0..511
  const int xcd = bid & 7;
  const int rest = bid >> 3;             // 0..63
  const int pan = (rest & 3) * 8 + xcd;  // XCD-pinned (b,h) panel 0..31
  const int slab = rest >> 2;            // 0..15
  const int b = pan >> 4, h = pan & 15;
  const int tid = threadIdx.x;
  const int wid = tid >> 6;
  const int lane = tid & 63;
  const int l15 = lane & 15, lg = lane >> 4;
  const int q0 = slab * 128 + wid * 16;

  const unsigned short* qptr = Qb + ((size_t)(b * SEQ + q0 + l15) * HIDN + h * HDIM + lg * 8);
  const bf16x8 bq0 = *(const bf16x8*)qptr;
  const bf16x8 bq1 = *(const bf16x8*)(qptr + 32);

  const float C = 0.18033688011112042f;  // (1/8) * log2(e)

  const unsigned short* kpanel = Kb + (size_t)b * SEQ * HIDN + h * HDIM;
  const unsigned short* vpanel = Vt + (size_t)h * HDIM * MTOT + b * SEQ;

  #define STAGE_K(buf, c) { \
    _Pragma("unroll") \
    for (int i = 0; i < 2; ++i) { \
      int row = wid * 8 + i * 64 + (lane >> 3); \
      const unsigned short* src = kpanel + (size_t)((c) * 128 + row) * HIDN + (lane & 7) * 8; \
      gload16(src, (char*)Ks[buf] + wid * 1024 + i * 8192); \
    } }
  #define STAGE_V(buf, c) { \
    _Pragma("unroll") \
    for (int i = 0; i < 2; ++i) { \
      int dl = wid * 4 + i * 32 + (lane >> 4); \
      const unsigned short* src = vpanel + (size_t)dl * MTOT + (c) * 128 + (lane & 15) * 8; \
      gload16(src, (char*)Vs[buf] + wid * 1024 + i * 8192); \
    } }

  STAGE_K(0, 0); STAGE_V(0, 0);
  __builtin_amdgcn_sched_barrier(0);
  asm volatile("s_waitcnt vmcnt(0)" ::: "memory");
  __builtin_amdgcn_s_barrier();
  __builtin_amdgcn_sched_barrier(0);

  float sm = 0.f;
  f32x4 pv[4] = {};

  for (int c = 0; c < 16; ++c) {
    const int cur = c & 1;
    if (c < 15) { STAGE_K(cur ^ 1, c + 1); STAGE_V(cur ^ 1, c + 1); }
    __builtin_amdgcn_sched_barrier(0);

    // QK^T from LDS (swizzled reads)
    f32x4 acc[8] = {};
    #pragma unroll
    for (int kf = 0; kf < 8; ++kf) {
      const int rowL = kf * 16 + l15;
      const char* kr = (const char*)Ks[cur] + rowL * 128;
      bf16x8 a0 = *(const bf16x8*)(kr + ((lg    ) ^ (rowL & 7)) * 16);
      bf16x8 a1 = *(const bf16x8*)(kr + ((lg + 4) ^ (rowL & 7)) * 16);
      acc[kf] = MFMA16(a0, bq0, acc[kf]);
      acc[kf] = MFMA16(a1, bq1, acc[kf]);
    }

    #pragma unroll
    for (int t = 0; t < 4; ++t) {
      float4 s0, s1;
      s0.x = exp2f(acc[2 * t][0] * C);
      s0.y = exp2f(acc[2 * t][1] * C);
      s0.z = exp2f(acc[2 * t][2] * C);
      s0.w = exp2f(acc[2 * t][3] * C);
      s1.x = exp2f(acc[2 * t + 1][0] * C);
      s1.y = exp2f(acc[2 * t + 1][1] * C);
      s1.z = exp2f(acc[2 * t + 1][2] * C);
      s1.w = exp2f(acc[2 * t + 1][3] * C);
      sm += ((s0.x + s0.y) + (s0.z + s0.w)) + ((s1.x + s1.y) + (s1.z + s1.w));

      union PKu { h16x2 h2[4]; f16x8 h8; } pk;
      pk.h2[0] = __builtin_amdgcn_cvt_pkrtz(s0.x, s0.y);
      pk.h2[1] = __builtin_amdgcn_cvt_pkrtz(s0.z, s0.w);
      pk.h2[2] = __builtin_amdgcn_cvt_pkrtz(s1.x, s1.y);
      pk.h2[3] = __builtin_amdgcn_cvt_pkrtz(s1.z, s1.w);

      #pragma unroll
      for (int nf = 0; nf < 4; ++nf) {
        const int d = nf * 16 + l15;
        f16x8 bv = *(const f16x8*)((const char*)Vs[cur] + d * 256 + (((t * 4 + lg) ^ l15)) * 16);
        pv[nf] = MFMAH16(pk.h8, bv, pv[nf]);
      }
    }

    __builtin_amdgcn_sched_barrier(0);
    asm volatile("s_waitcnt vmcnt(0)" ::: "memory");
    __builtin_amdgcn_s_barrier();
    __builtin_amdgcn_sched_barrier(0);
  }

  // row sums -> inverses (lane-local: q = l15)
  #pragma unroll
  for (int off = 16; off <= 32; off <<= 1) sm += __shfl_xor(sm, off, 64);
  const float inv = __builtin_amdgcn_rcpf(sm);
  if (lane < 16) invs[(size_t)(b * NHEAD + h) * SEQ + q0 + lane] = inv;

  // attv: scale unnormalized PV by inv(q)
  float* av = out + (size_t)NB * NHEAD * SEQ * SEQ
            + ((size_t)(b * NHEAD + h) * SEQ + q0 + 4 * lg) * HDIM + l15;
  #pragma unroll
  for (int e = 0; e < 4; ++e) {
    const float invq = __shfl(inv, 4 * lg + e, 64);
    #pragma unroll
    for (int nf = 0; nf < 4; ++nf)
      __builtin_nontemporal_store(pv[nf][e] * invq, av + (size_t)e * HDIM + nf * 16);
  }
  #undef STAGE_K
  #undef STAGE_V
}

// ---------------- kernel 4: score_emit — recompute QK, row-contiguous fp32 -
// 512 threads = 8 waves; block owns 8 consecutive 16-row q-tiles of a panel.
// Phase 1: each wave computes 2 key-chunks (K direct from L2, swizzle-decoded),
// exp, packs unnormalized fp16 P into XOR-swizzled LDS (16 rows x 2048).
// Phase 2: each wave emits 2 FULL rows: ds_read -> fp32 * inv -> 8KB-
// contiguous NT stores. vmcnt (stores) is NEVER waited on.
__global__ __launch_bounds__(512, 2) void score_emit(
    const unsigned short* __restrict__ Qb,
    const unsigned short* __restrict__ Kb,
    const float* __restrict__ invs,
    float* __restrict__ out)
{
  __shared__ unsigned short P[16 * 2048];   // 64KB

  const int bid = blockIdx.x;            // 0..511
  const int xcd = bid & 7;
  const int rest = bid >> 3;             // 0..63
  const int pan = (rest & 3) * 8 + xcd;  // XCD-pinned (b,h) panel 0..31
  const int blkp = rest >> 2;            // 0..15 block-within-panel
  const int b = pan >> 4, h = pan & 15;
  const int tid = threadIdx.x;
  const int wid = tid >> 6;
  const int lane = tid & 63;
  const int l15 = lane & 15, lg = lane >> 4;

  const float C = 0.18033688011112042f;
  const unsigned short* kpanel = Kb + (size_t)b * SEQ * HIDN + h * HDIM;
  const size_t panrow0 = (size_t)(b * NHEAD + h) * SEQ;

  for (int tt = 0; tt < 8; ++tt) {
    const int q0 = (blkp * 8 + tt) * 16;

    const unsigned short* qptr = Qb + ((size_t)(b * SEQ + q0 + l15) * HIDN + h * HDIM + lg * 8);
    const bf16x8 bq0 = *(const bf16x8*)qptr;
    const bf16x8 bq1 = *(const bf16x8*)(qptr + 32);

    // ---- phase 1: compute 2 chunks, pack into LDS ----
    #pragma unroll
    for (int i = 0; i < 2; ++i) {
      const int c = wid * 2 + i;
      f32x4 acc[8] = {};
      #pragma unroll
      for (int kf = 0; kf < 8; ++kf) {
        const int s = c * 128 + kf * 16 + l15;     // storage row
        const unsigned short* kr = kpanel + (size_t)s * HIDN;
        bf16x8 a0 = *(const bf16x8*)(kr + ((lg      ^ (s & 7))) * 8);
        bf16x8 a1 = *(const bf16x8*)(kr + (((lg + 4) ^ (s & 7))) * 8);
        acc[kf] = MFMA16(a0, bq0, acc[kf]);
        acc[kf] = MFMA16(a1, bq1, acc[kf]);
      }
      #pragma unroll
      for (int t = 0; t < 4; ++t) {
        float4 s0, s1;
        s0.x = exp2f(acc[2 * t][0] * C);
        s0.y = exp2f(acc[2 * t][1] * C);
        s0.z = exp2f(acc[2 * t][2] * C);
        s0.w = exp2f(acc[2 * t][3] * C);
        s1.x = exp2f(acc[2 * t + 1][0] * C);
        s1.y = exp2f(acc[2 * t + 1][1] * C);
        s1.z = exp2f(acc[2 * t + 1][2] * C);
        s1.w = exp2f(acc[2 * t + 1][3] * C);

        union PKu { h16x2 h2[4]; u32x4 u4; } pk;
        pk.h2[0] = __builtin_amdgcn_cvt_pkrtz(s0.x, s0.y);
        pk.h2[1] = __builtin_amdgcn_cvt_pkrtz(s0.z, s0.w);
        pk.h2[2] = __builtin_amdgcn_cvt_pkrtz(s1.x, s1.y);
        pk.h2[3] = __builtin_amdgcn_cvt_pkrtz(s1.z, s1.w);

        const int off = c * 256 + ((((t * 4 + lg) ^ l15)) << 4);
        *(u32x4*)((char*)P + l15 * 4096 + off) = pk.u4;
      }
    }

    asm volatile("s_waitcnt lgkmcnt(0)" ::: "memory");
    __builtin_amdgcn_s_barrier();
    __builtin_amdgcn_sched_barrier(0);

    // ---- phase 2: emit rows 2*wid, 2*wid+1 (8KB contiguous each) ----
    #pragma unroll
    for (int i = 0; i < 2; ++i) {
      const int r = wid * 2 + i;
      const float invr = invs[panrow0 + q0 + r];
      float* orow = out + (panrow0 + q0 + r) * SEQ;
      #pragma unroll
      for (int g = 0; g < 8; ++g) {
        const int o = g * 512 + lane * 8;             // logical byte in row
        const int ph = o ^ ((r & 15) << 4);           // swizzled
        uint2 w = *(const uint2*)((const char*)P + r * 4096 + ph);
        f32x4 ov;
        ov[0] = h2f((unsigned short)(w.x & 0xffff)) * invr;
        ov[1] = h2f((unsigned short)(w.x >> 16)) * invr;
        ov[2] = h2f((unsigned short)(w.y & 0xffff)) * invr;
        ov[3] = h2f((unsigned short)(w.y >> 16)) * invr;
        __builtin_nontemporal_store(ov, (f32x4*)(orow + (o >> 1)));
      }
    }

    asm volatile("s_waitcnt lgkmcnt(0)" ::: "memory");
    __builtin_amdgcn_s_barrier();
    __builtin_amdgcn_sched_barrier(0);
  }
}

extern "C" void kernel_launch(void* const* d_in, const int* in_sizes, int n_in,
                              void* d_out, int out_size, void* d_ws, size_t ws_size,
                              hipStream_t stream)
{
  const float* x  = (const float*)d_in[0];
  const float* wq = (const float*)d_in[1];
  const float* wk = (const float*)d_in[2];
  const float* wv = (const float*)d_in[3];
  float* out = (float*)d_out;
  unsigned short* ws = (unsigned short*)d_ws;

  unsigned short* xb  = ws;              // dead after qkv; invs aliases it
  unsigned short* wqb = ws + 4194304;
  unsigned short* wkb = ws + 5242880;
  unsigned short* wvb = ws + 6291456;
  unsigned short* Qb  = ws + 7340032;
  unsigned short* Kb  = ws + 11534336;
  unsigned short* Vt  = ws + 15728640;   // fp16
  float* invs = (float*)ws;              // 256KB, aliases dead xb

  cvt_bf16<<<7168, 256, 0, stream>>>(x, wq, wk, wv, ws);
  qkv_gemm<<<dim3(8, 32, 3), 256, 0, stream>>>(xb, wqb, wkb, wvb, Qb, Kb, Vt);
  attn_pv<<<512, 512, 0, stream>>>(Qb, Kb, Vt, invs, out);
  score_emit<<<512, 512, 0, stream>>>(Qb, Kb, invs, out);
}